// Round 1
// baseline (7573.390 us; speedup 1.0000x reference)
//
#include <hip/hip_runtime.h>
#include <hip/hip_fp16.h>
#include <stdint.h>

typedef _Float16 h8 __attribute__((ext_vector_type(8)));
typedef float f4 __attribute__((ext_vector_type(4)));

#define MFMA16(a, b, c) __builtin_amdgcn_mfma_f32_16x16x32_f16((a), (b), (c), 0, 0, 0)

#define RSLOT 16
#define FSTR 260

constexpr size_t HBUF_OFF = 0;
constexpr size_t HBUF_BYTES = 10ull * RSLOT * 64 * 64 * 8 * 2;   // 10,485,760
constexpr size_t X_OFF = HBUF_OFF + HBUF_BYTES;
constexpr size_t X_BYTES = 256ull * 4096 * 2;                    // 2,097,152
constexpr size_t STRM_OFF = X_OFF + X_BYTES;
constexpr size_t STRM_BYTES = 234ull * 15360;                    // 3,594,240
constexpr size_t RDY_OFF = STRM_OFF + STRM_BYTES;
constexpr size_t DONE_OFF = RDY_OFF + 10ull * FSTR * 4;
constexpr size_t WS_NEED = DONE_OFF + 10ull * FSTR * 4;

__device__ __forceinline__ void spin_ge(int* p, int tgt) {
  int it = 0;
  while (__hip_atomic_load(p, __ATOMIC_RELAXED, __HIP_MEMORY_SCOPE_AGENT) < tgt) {
    __builtin_amdgcn_s_sleep(1);
    if (++it > 50000) break;   // bail: wrong answer beats a hang
  }
}

__device__ __forceinline__ int colrow_main(int c, int S, int hbase) {
  // column -> weight row for main layers. cols 0..63: gate=c>>4, h=c&15 (vertical quads)
  // cols 64..79: spares: h=16+(j>>2), gate=j&3
  int g, hl;
  if (c < 64) { g = c >> 4; hl = c & 15; }
  else { int j = c - 64; g = j & 3; hl = 16 + (j >> 2); }
  if (hl >= S) hl = S - 1;   // dummy col clamp (S==19 CUs)
  return g * 512 + hbase + hl;
}

__device__ __forceinline__ float sigm(float x) {
  return __fdividef(1.f, 1.f + __expf(-x));
}
__device__ __forceinline__ float tanh_f(float x) {
  return 1.f - __fdividef(2.f, __expf(2.f * x) + 1.f);
}

// ---------------- prep kernels ----------------

__global__ __launch_bounds__(256) void zero_kernel(char* ws) {
  int i = blockIdx.x * 256 + threadIdx.x;
  if (i < 163840) {                       // zero slot 0 of each layer's h ring
    int layer = i >> 14;                  // 16384 ints per slot
    int w = i & 16383;
    ((int*)(ws + HBUF_OFF))[(size_t)layer * RSLOT * 16384 + w] = 0;
  } else {
    int j = i - 163840;
    if (j < 2 * 10 * FSTR) ((int*)(ws + RDY_OFF))[j] = 0;   // ready + done
  }
}

__global__ __launch_bounds__(256) void xprep_kernel(const float* __restrict__ X, char* ws) {
  int u = blockIdx.x * 256 + threadIdx.x;       // one 8-elem chunk each
  if (u >= 131072) return;
  int t = u >> 9, rem = u & 511, kg = rem >> 6, b = rem & 63;
  const float* src = X + ((size_t)b * 256 + t) * 64 + kg * 8;
  h8 v;
#pragma unroll
  for (int j = 0; j < 8; ++j) v[j] = (_Float16)src[j];
  *(h8*)(ws + X_OFF + (size_t)u * 16) = v;
}

__global__ __launch_bounds__(256) void wsprep_kernel(const float* __restrict__ Whh, char* ws) {
  int u = blockIdx.x * 256 + threadIdx.x;
  if (u >= 234 * 15 * 64) return;
  int cu = u / 960, rem = u % 960;
  int f = rem >> 6, l = rem & 63;
  int ktm = f / 5, nt = f % 5, kt = 29 + ktm;
  int L = 1 + cu / 26, cl = cu % 26;
  int S = cl < 18 ? 20 : 19;
  int hbase = cl < 18 ? 20 * cl : 360 + 19 * (cl - 18);
  int c = 16 * nt + (l & 15);
  int row = colrow_main(c, S, hbase);
  int k = kt * 32 + (l >> 4) * 8;               // >= 928, all in W_hh half
  const float* src = Whh + ((size_t)L * 2048 + row) * 512 + (k - 512);
  h8 v;
#pragma unroll
  for (int j = 0; j < 8; ++j) v[j] = (_Float16)src[j];
  *(h8*)(ws + STRM_OFF + (size_t)cu * 15360 + (size_t)f * 1024 + (size_t)l * 16) = v;
}

// ---------------- main persistent kernel ----------------

__global__ __launch_bounds__(256, 1) void lstm_fused(
    const float* __restrict__ X, const float* __restrict__ Wih0,
    const float* __restrict__ Wih, const float* __restrict__ Whh,
    const float* __restrict__ bih, const float* __restrict__ bhh,
    const float* __restrict__ Wout, const float* __restrict__ bout,
    float* __restrict__ out, char* __restrict__ ws)
{
  extern __shared__ char lds[];
  const int blk = blockIdx.x;
  const int role = (blk & 7) * 32 + (blk >> 3);   // XCD-contiguous role mapping
  if (role >= 250) return;

  __half* hbuf = (__half*)(ws + HBUF_OFF);
  const __half* xt = (const __half*)(ws + X_OFF);
  int* rdy = (int*)(ws + RDY_OFF);
  int* dn  = (int*)(ws + DONE_OFF);

  const int tid = threadIdx.x;
  const int lane = tid & 63;
  const int wv = tid >> 6;
  const int pp = lane & 15;
  const int lg = lane >> 4;
  const int n = wv & 1, m = wv >> 1;
  const int ab0 = lg * 512 + (16 * (2 * m) + pp) * 8;
  const int ab1 = ab0 + 128;

  if (role < 16) {
    // ================= layer 0 + head =================
    const int cu = role;
    const int hbase = cu * 32;
    // stage W0 into LDS: [128 cols][576 k] fp16, stride 1152B, XOR swizzle
    for (int ch = tid; ch < 9216; ch += 256) {
      int c = ch / 72, kc = (ch % 72) * 8;
      int g = (c >> 4) & 3;
      int hl = ((c >> 6) << 4) + (c & 15);
      int row = g * 512 + hbase + hl;
      const float* src = (kc < 64) ? (Wih0 + (size_t)row * 64 + kc)
                                   : (Whh + (size_t)row * 512 + (kc - 64));
      h8 v;
#pragma unroll
      for (int j = 0; j < 8; ++j) v[j] = (_Float16)src[j];
      uint32_t off = ((uint32_t)(c * 1152 + kc * 2)) ^ (uint32_t)((c & 7) << 4);
      *(h8*)(lds + off) = v;
    }
    float bias0[4];
#pragma unroll
    for (int j = 0; j < 4; ++j) {
      int row = j * 512 + hbase + n * 16 + pp;
      bias0[j] = bih[row] + bhh[row];
    }
    __syncthreads();

    float cv[2][4] = {{0.f,0.f,0.f,0.f},{0.f,0.f,0.f,0.f}};
    int* rdy0 = rdy;
    int* rdy9 = rdy + 9 * FSTR;
    int* dn0 = dn;
    int* dn9 = dn + 9 * FSTR;

    for (int t = 0; t < 266; ++t) {
      // ---- head for step t-10 ----
      if (t >= 10) {
        const int th = t - 10;
        spin_ge(rdy9 + th, 26);
        (void)__hip_atomic_load(rdy9 + th, __ATOMIC_ACQUIRE, __HIP_MEMORY_SCOPE_AGENT);
        const __half* h9 = hbuf + ((size_t)9 * RSLOT + ((th + 1) & 15)) * 32768;
        const int b = lane;
        const int dp = cu * 4 + wv;
        float acc = bout[dp];
        const float* wrow = Wout + (size_t)dp * 512;
#pragma unroll 8
        for (int kg = 0; kg < 64; ++kg) {
          h8 hv = *(const h8*)(h9 + (size_t)kg * 512 + b * 8);
          f4 w0 = *(const f4*)(wrow + kg * 8);
          f4 w1 = *(const f4*)(wrow + kg * 8 + 4);
          acc += (float)hv[0]*w0[0] + (float)hv[1]*w0[1] + (float)hv[2]*w0[2] + (float)hv[3]*w0[3]
               + (float)hv[4]*w1[0] + (float)hv[5]*w1[1] + (float)hv[6]*w1[2] + (float)hv[7]*w1[3];
        }
        out[(size_t)b * 16384 + (size_t)th * 64 + dp] = acc;
      }
      // ---- layer-0 cell t ----
      if (t <= 255) {
        if (t > 0) spin_ge(rdy0 + t - 1, 16);
        if (t >= 15) spin_ge(dn0 + t - 15, (t == 15) ? 16 : 42);
        if (t > 0) (void)__hip_atomic_load(rdy0 + t - 1, __ATOMIC_ACQUIRE, __HIP_MEMORY_SCOPE_AGENT);
        const __half* Ax = xt + (size_t)t * 4096;
        const __half* As = hbuf + (size_t)(t & 15) * 32768;        // layer0 self, slot(t-1)
        f4 acc[2][4];
#pragma unroll
        for (int mi = 0; mi < 2; ++mi)
#pragma unroll
          for (int j = 0; j < 4; ++j) acc[mi][j] = (f4){0.f, 0.f, 0.f, 0.f};

#pragma unroll
        for (int kt = 0; kt < 2; ++kt) {                            // x part (K 0..63)
          h8 a0 = *(const h8*)(Ax + kt * 2048 + ab0);
          h8 a1 = *(const h8*)(Ax + kt * 2048 + ab1);
#pragma unroll
          for (int j = 0; j < 4; ++j) {
            int c = 16 * (4 * n + j) + pp;
            uint32_t off = ((uint32_t)(c * 1152 + kt * 64 + lg * 16)) ^ (uint32_t)((c & 7) << 4);
            h8 bv = *(const h8*)(lds + off);
            acc[0][j] = MFMA16(a0, bv, acc[0][j]);
            acc[1][j] = MFMA16(a1, bv, acc[1][j]);
          }
        }
#pragma unroll 4
        for (int kt = 2; kt < 18; ++kt) {                           // recurrent part
          h8 a0 = *(const h8*)(As + (kt - 2) * 2048 + ab0);
          h8 a1 = *(const h8*)(As + (kt - 2) * 2048 + ab1);
#pragma unroll
          for (int j = 0; j < 4; ++j) {
            int c = 16 * (4 * n + j) + pp;
            uint32_t off = ((uint32_t)(c * 1152 + kt * 64 + lg * 16)) ^ (uint32_t)((c & 7) << 4);
            h8 bv = *(const h8*)(lds + off);
            acc[0][j] = MFMA16(a0, bv, acc[0][j]);
            acc[1][j] = MFMA16(a1, bv, acc[1][j]);
          }
        }
        // epilogue: quads are vertical (nt j = gate j), h = hbase + n*16 + pp
        __half* Hd = hbuf + (size_t)((t + 1) & 15) * 32768;
        const int hg = hbase + n * 16 + pp;
#pragma unroll
        for (int mi = 0; mi < 2; ++mi) {
          int bbb = 16 * (2 * m + mi) + 4 * lg;
#pragma unroll
          for (int r = 0; r < 4; ++r) {
            float gi = sigm(acc[mi][0][r] + bias0[0]);
            float gf = sigm(acc[mi][1][r] + bias0[1]);
            float gg = tanh_f(acc[mi][2][r] + bias0[2]);
            float go = sigm(acc[mi][3][r] + bias0[3]);
            float c2 = gf * cv[mi][r] + gi * gg;
            cv[mi][r] = c2;
            float hh = go * tanh_f(c2);
            Hd[(size_t)(hg >> 3) * 512 + (bbb + r) * 8 + (hg & 7)] = __float2half(hh);
          }
        }
      }
      __syncthreads();
      if (tid == 0) {
        if (t <= 255) {
          __hip_atomic_fetch_add(rdy0 + t, 1, __ATOMIC_RELEASE, __HIP_MEMORY_SCOPE_AGENT);
          __hip_atomic_fetch_add(dn0 + t, 1, __ATOMIC_RELAXED, __HIP_MEMORY_SCOPE_AGENT);
        }
        if (t >= 10)
          __hip_atomic_fetch_add(dn9 + (t - 9), 1, __ATOMIC_RELAXED, __HIP_MEMORY_SCOPE_AGENT);
      }
    }
    return;
  }

  // ================= layers 1..9 =================
  const int cuIdx = role - 16;
  const int L = 1 + cuIdx / 26;
  const int cl = cuIdx % 26;
  const int S = cl < 18 ? 20 : 19;
  const int hbase = cl < 18 ? 20 * cl : 360 + 19 * (cl - 18);
  const float* WihL = Wih + (size_t)(L - 1) * 1048576;
  const float* WhhL = Whh + (size_t)L * 1048576;
  const float* bihL = bih + L * 2048;
  const float* bhhL = bhh + L * 2048;

  // stage W into LDS: [80 cols][928 k] fp16, stride 1856B, XOR swizzle
  for (int ch = tid; ch < 9280; ch += 256) {
    int c = ch / 116, kc = (ch % 116) * 8;
    int row = colrow_main(c, S, hbase);
    const float* src = (kc < 512) ? (WihL + (size_t)row * 512 + kc)
                                  : (WhhL + (size_t)row * 512 + (kc - 512));
    h8 v;
#pragma unroll
    for (int j = 0; j < 8; ++j) v[j] = (_Float16)src[j];
    uint32_t off = ((uint32_t)(c * 1856 + kc * 2)) ^ (uint32_t)((c & 7) << 4);
    *(h8*)(lds + off) = v;
  }
  float biasv[4], bsp[4];
#pragma unroll
  for (int j = 0; j < 4; ++j) {
    int row = colrow_main(16 * j + pp, S, hbase);
    biasv[j] = bihL[row] + bhhL[row];
    int rs = colrow_main(64 + 4 * (pp >> 2) + j, S, hbase);
    bsp[j] = bihL[rs] + bhhL[rs];
  }
  __syncthreads();

  int* rdyP = rdy + (L - 1) * FSTR;
  int* rdyL = rdy + L * FSTR;
  int* dnP = dn + (L - 1) * FSTR;
  int* dnL = dn + L * FSTR;
  const int ncuP = (L == 1) ? 16 : 26;
  const int dnTgt = (L == 9) ? 42 : 52;
  const int ntA = n ? 3 : 0;
  const int cA = 16 * ntA + pp, cB = cA + 16, c2c = 32 + pp;
  const char* strm = ws + STRM_OFF + (size_t)cuIdx * 15360;
  float* xch = (float*)(lds + 148480);

  float cv[2][2] = {{0.f,0.f},{0.f,0.f}};
  float csp[2][2] = {{0.f,0.f},{0.f,0.f}};

  for (int t = 0; t < 256; ++t) {
    spin_ge(rdyP + t, ncuP);
    if (t > 0) spin_ge(rdyL + t - 1, 26);
    if (t >= 15) spin_ge(dnL + t - 15, (t == 15) ? 26 : dnTgt);
    (void)__hip_atomic_load(rdyP + t, __ATOMIC_ACQUIRE, __HIP_MEMORY_SCOPE_AGENT);

    const __half* Abot = hbuf + ((size_t)(L - 1) * RSLOT + ((t + 1) & 15)) * 32768;
    const __half* Asel = hbuf + ((size_t)L * RSLOT + (t & 15)) * 32768;

    f4 acc[2][3];
#pragma unroll
    for (int mi = 0; mi < 2; ++mi)
#pragma unroll
      for (int j = 0; j < 3; ++j) acc[mi][j] = (f4){0.f, 0.f, 0.f, 0.f};

    // kt 0..15: A from layer below; nt2 handled by n==0 waves
#pragma unroll 4
    for (int kt = 0; kt < 16; ++kt) {
      h8 a0 = *(const h8*)(Abot + kt * 2048 + ab0);
      h8 a1 = *(const h8*)(Abot + kt * 2048 + ab1);
      uint32_t o0 = ((uint32_t)(cA * 1856 + kt * 64 + lg * 16)) ^ (uint32_t)((cA & 7) << 4);
      uint32_t o1 = ((uint32_t)(cB * 1856 + kt * 64 + lg * 16)) ^ (uint32_t)((cB & 7) << 4);
      h8 b0 = *(const h8*)(lds + o0);
      h8 b1 = *(const h8*)(lds + o1);
      acc[0][0] = MFMA16(a0, b0, acc[0][0]);
      acc[1][0] = MFMA16(a1, b0, acc[1][0]);
      acc[0][1] = MFMA16(a0, b1, acc[0][1]);
      acc[1][1] = MFMA16(a1, b1, acc[1][1]);
      if (n == 0) {
        uint32_t o2 = ((uint32_t)(c2c * 1856 + kt * 64 + lg * 16)) ^ (uint32_t)((c2c & 7) << 4);
        h8 b2 = *(const h8*)(lds + o2);
        acc[0][2] = MFMA16(a0, b2, acc[0][2]);
        acc[1][2] = MFMA16(a1, b2, acc[1][2]);
      }
    }
    // kt 16..28: A from own layer (t-1); nt2 handled by n==1 waves
#pragma unroll 4
    for (int kt = 16; kt < 29; ++kt) {
      h8 a0 = *(const h8*)(Asel + (kt - 16) * 2048 + ab0);
      h8 a1 = *(const h8*)(Asel + (kt - 16) * 2048 + ab1);
      uint32_t o0 = ((uint32_t)(cA * 1856 + kt * 64 + lg * 16)) ^ (uint32_t)((cA & 7) << 4);
      uint32_t o1 = ((uint32_t)(cB * 1856 + kt * 64 + lg * 16)) ^ (uint32_t)((cB & 7) << 4);
      h8 b0 = *(const h8*)(lds + o0);
      h8 b1 = *(const h8*)(lds + o1);
      acc[0][0] = MFMA16(a0, b0, acc[0][0]);
      acc[1][0] = MFMA16(a1, b0, acc[1][0]);
      acc[0][1] = MFMA16(a0, b1, acc[0][1]);
      acc[1][1] = MFMA16(a1, b1, acc[1][1]);
      if (n == 1) {
        uint32_t o2 = ((uint32_t)(c2c * 1856 + kt * 64 + lg * 16)) ^ (uint32_t)((c2c & 7) << 4);
        h8 b2 = *(const h8*)(lds + o2);
        acc[0][2] = MFMA16(a0, b2, acc[0][2]);
        acc[1][2] = MFMA16(a1, b2, acc[1][2]);
      }
    }
    // kt 29..31: B from streamed fragment image
#pragma unroll
    for (int kt = 29; kt < 32; ++kt) {
      h8 a0 = *(const h8*)(Asel + (kt - 16) * 2048 + ab0);
      h8 a1 = *(const h8*)(Asel + (kt - 16) * 2048 + ab1);
      h8 b0 = *(const h8*)(strm + ((kt - 29) * 5 + ntA) * 1024 + lane * 16);
      h8 b1 = *(const h8*)(strm + ((kt - 29) * 5 + ntA + 1) * 1024 + lane * 16);
      acc[0][0] = MFMA16(a0, b0, acc[0][0]);
      acc[1][0] = MFMA16(a1, b0, acc[1][0]);
      acc[0][1] = MFMA16(a0, b1, acc[0][1]);
      acc[1][1] = MFMA16(a1, b1, acc[1][1]);
      if (n == 1) {
        h8 b2 = *(const h8*)(strm + ((kt - 29) * 5 + 2) * 1024 + lane * 16);
        acc[0][2] = MFMA16(a0, b2, acc[0][2]);
        acc[1][2] = MFMA16(a1, b2, acc[1][2]);
      }
    }

    // cross-wave exchange: n0 keeps rows {0,1}, n1 rows {2,3}; merge split nt2
    {
      int idx = 0;
#pragma unroll
      for (int mi = 0; mi < 2; ++mi)
#pragma unroll
        for (int ntl = 0; ntl < 3; ++ntl)
#pragma unroll
          for (int rj = 0; rj < 2; ++rj) {
            float sv = (n == 0) ? acc[mi][ntl][2 + rj] : acc[mi][ntl][rj];
            xch[(wv * 12 + idx) * 64 + lane] = sv;
            ++idx;
          }
    }
    __syncthreads();
    float F[2][5][2];
    {
      const int pw = wv ^ 1;
#pragma unroll
      for (int mi = 0; mi < 2; ++mi)
#pragma unroll
        for (int rj = 0; rj < 2; ++rj) {
          float r0 = xch[(pw * 12 + (mi * 3 + 0) * 2 + rj) * 64 + lane];
          float r1 = xch[(pw * 12 + (mi * 3 + 1) * 2 + rj) * 64 + lane];
          float r2 = xch[(pw * 12 + (mi * 3 + 2) * 2 + rj) * 64 + lane];
          float o0, o1, o2;
          if (n == 0) { o0 = acc[mi][0][rj]; o1 = acc[mi][1][rj]; o2 = acc[mi][2][rj]; }
          else        { o0 = acc[mi][0][2 + rj]; o1 = acc[mi][1][2 + rj]; o2 = acc[mi][2][2 + rj]; }
          if (n == 0) {
            F[mi][0][rj] = o0; F[mi][1][rj] = o1; F[mi][2][rj] = o2 + r2;
            F[mi][3][rj] = r0; F[mi][4][rj] = r1;
          } else {
            F[mi][0][rj] = r0; F[mi][1][rj] = r1; F[mi][2][rj] = o2 + r2;
            F[mi][3][rj] = o0; F[mi][4][rj] = o1;
          }
        }
    }

    // epilogue
    __half* Hd = hbuf + ((size_t)L * RSLOT + ((t + 1) & 15)) * 32768;
    const int rrb = n ? 2 : 0;
    const int pm = lane & 3;
#pragma unroll
    for (int mi = 0; mi < 2; ++mi) {
#pragma unroll
      for (int rj = 0; rj < 2; ++rj) {
        int bbb = 16 * (2 * m + mi) + 4 * lg + rrb + rj;
        // vertical quad: h = hbase + pp
        float gi = sigm(F[mi][0][rj] + biasv[0]);
        float gf = sigm(F[mi][1][rj] + biasv[1]);
        float gg = tanh_f(F[mi][2][rj] + biasv[2]);
        float go = sigm(F[mi][3][rj] + biasv[3]);
        float cc = gf * cv[mi][rj] + gi * gg;
        cv[mi][rj] = cc;
        float hh = go * tanh_f(cc);
        {
          int hg = hbase + pp;
          Hd[(size_t)(hg >> 3) * 512 + bbb * 8 + (hg & 7)] = __float2half(hh);
        }
        // spare (nt4): gather quad across 4-lane group
        float va = F[mi][4][rj];
        float vb = __shfl_xor(va, 1);
        float vc = __shfl_xor(va, 2);
        float vd = __shfl_xor(vb, 2);
        float q0 = (pm & 2) ? ((pm & 1) ? vd : vc) : ((pm & 1) ? vb : va);
        float q1 = (pm & 2) ? ((pm & 1) ? vc : vd) : ((pm & 1) ? va : vb);
        float q2 = (pm & 2) ? ((pm & 1) ? vb : va) : ((pm & 1) ? vd : vc);
        float q3 = (pm & 2) ? ((pm & 1) ? va : vb) : ((pm & 1) ? vc : vd);
        float si = sigm(q0 + bsp[0]);
        float sf = sigm(q1 + bsp[1]);
        float sg = tanh_f(q2 + bsp[2]);
        float so = sigm(q3 + bsp[3]);
        float c3 = sf * csp[mi][rj] + si * sg;
        csp[mi][rj] = c3;
        float hs = so * tanh_f(c3);
        int hj = 16 + (pp >> 2);
        if (pm == 0 && hj < S) {
          int hg = hbase + hj;
          Hd[(size_t)(hg >> 3) * 512 + bbb * 8 + (hg & 7)] = __float2half(hs);
        }
      }
    }

    __syncthreads();
    if (tid == 0) {
      __hip_atomic_fetch_add(rdyL + t, 1, __ATOMIC_RELEASE, __HIP_MEMORY_SCOPE_AGENT);
      __hip_atomic_fetch_add(dnP + t + 1, 1, __ATOMIC_RELAXED, __HIP_MEMORY_SCOPE_AGENT);
      __hip_atomic_fetch_add(dnL + t, 1, __ATOMIC_RELAXED, __HIP_MEMORY_SCOPE_AGENT);
    }
  }
}

// ---------------- host ----------------

extern "C" void kernel_launch(void* const* d_in, const int* in_sizes, int n_in,
                              void* d_out, int out_size, void* d_ws, size_t ws_size,
                              hipStream_t stream) {
  const float* X    = (const float*)d_in[0];
  const float* Wih0 = (const float*)d_in[1];
  const float* Wih  = (const float*)d_in[2];
  const float* Whh  = (const float*)d_in[3];
  const float* bihp = (const float*)d_in[4];
  const float* bhhp = (const float*)d_in[5];
  const float* Wout = (const float*)d_in[6];
  const float* bout = (const float*)d_in[7];
  float* out = (float*)d_out;
  char* ws = (char*)d_ws;
  (void)in_sizes; (void)n_in; (void)out_size;
  if (ws_size < WS_NEED) return;   // visible failure, no corruption

  hipFuncSetAttribute((const void*)lstm_fused,
                      hipFuncAttributeMaxDynamicSharedMemorySize, 163840);

  zero_kernel<<<661, 256, 0, stream>>>(ws);
  xprep_kernel<<<512, 256, 0, stream>>>(X, ws);
  wsprep_kernel<<<878, 256, 0, stream>>>(Whh, ws);
  lstm_fused<<<256, 256, 163840, stream>>>(X, Wih0, Wih, Whh, bihp, bhhp,
                                           Wout, bout, out, ws);
}

// Round 2
// 5396.326 us; speedup vs baseline: 1.4034x; 1.4034x over previous
//
#include <hip/hip_runtime.h>
#include <hip/hip_fp16.h>
#include <stdint.h>

typedef _Float16 h8 __attribute__((ext_vector_type(8)));
typedef float f4 __attribute__((ext_vector_type(4)));

#define MFMA16(a, b, c) __builtin_amdgcn_mfma_f32_16x16x32_f16((a), (b), (c), 0, 0, 0)

#define RSLOT 16
#define FSTR 260

constexpr size_t HBUF_OFF = 0;
constexpr size_t HBUF_BYTES = 10ull * RSLOT * 64 * 64 * 8 * 2;   // 10,485,760
constexpr size_t X_OFF = HBUF_OFF + HBUF_BYTES;
constexpr size_t X_BYTES = 256ull * 4096 * 2;                    // 2,097,152
constexpr size_t STRM_OFF = X_OFF + X_BYTES;
constexpr size_t STRM_BYTES = 234ull * 15360;                    // 3,594,240
constexpr size_t RDY_OFF = STRM_OFF + STRM_BYTES;
constexpr size_t DONE_OFF = RDY_OFF + 10ull * FSTR * 4;
constexpr size_t WS_NEED = DONE_OFF + 10ull * FSTR * 4;

// tid0-only spin; no fences (per-access coherence everywhere else)
__device__ __forceinline__ void spin_ge(int* p, int tgt) {
  int it = 0;
  while (__hip_atomic_load(p, __ATOMIC_RELAXED, __HIP_MEMORY_SCOPE_AGENT) < tgt) {
    __builtin_amdgcn_s_sleep(1);
    if (++it > 300000) break;   // bail: wrong answer beats a hang
  }
}

// device-coherent 16B load as two 8B relaxed agent atomics (sc1, no fence,
// compiler-tracked vmcnt)
__device__ __forceinline__ h8 ld_h8_dc(const __half* p) {
  const unsigned long long* q = (const unsigned long long*)p;
  unsigned long long lo = __hip_atomic_load(q,     __ATOMIC_RELAXED, __HIP_MEMORY_SCOPE_AGENT);
  unsigned long long hi = __hip_atomic_load(q + 1, __ATOMIC_RELAXED, __HIP_MEMORY_SCOPE_AGENT);
  union { unsigned long long u[2]; h8 v; } r;
  r.u[0] = lo; r.u[1] = hi;
  return r.v;
}

// device-coherent 2B store (write-through to coherence point)
__device__ __forceinline__ void st_h_dc(__half* p, float x) {
  __hip_atomic_store((unsigned short*)p, __half_as_ushort(__float2half(x)),
                     __ATOMIC_RELAXED, __HIP_MEMORY_SCOPE_AGENT);
}

__device__ __forceinline__ int colrow_main(int c, int S, int hbase) {
  int g, hl;
  if (c < 64) { g = c >> 4; hl = c & 15; }
  else { int j = c - 64; g = j & 3; hl = 16 + (j >> 2); }
  if (hl >= S) hl = S - 1;
  return g * 512 + hbase + hl;
}

__device__ __forceinline__ float sigm(float x) {
  return __fdividef(1.f, 1.f + __expf(-x));
}
__device__ __forceinline__ float tanh_f(float x) {
  return 1.f - __fdividef(2.f, __expf(2.f * x) + 1.f);
}

// ---------------- prep kernels ----------------

__global__ __launch_bounds__(256) void zero_kernel(char* ws) {
  int i = blockIdx.x * 256 + threadIdx.x;
  if (i < 163840) {
    int layer = i >> 14;
    int w = i & 16383;
    ((int*)(ws + HBUF_OFF))[(size_t)layer * RSLOT * 16384 + w] = 0;
  } else {
    int j = i - 163840;
    if (j < 2 * 10 * FSTR) ((int*)(ws + RDY_OFF))[j] = 0;
  }
}

__global__ __launch_bounds__(256) void xprep_kernel(const float* __restrict__ X, char* ws) {
  int u = blockIdx.x * 256 + threadIdx.x;
  if (u >= 131072) return;
  int t = u >> 9, rem = u & 511, kg = rem >> 6, b = rem & 63;
  const float* src = X + ((size_t)b * 256 + t) * 64 + kg * 8;
  h8 v;
#pragma unroll
  for (int j = 0; j < 8; ++j) v[j] = (_Float16)src[j];
  *(h8*)(ws + X_OFF + (size_t)u * 16) = v;
}

__global__ __launch_bounds__(256) void wsprep_kernel(const float* __restrict__ Whh, char* ws) {
  int u = blockIdx.x * 256 + threadIdx.x;
  if (u >= 234 * 15 * 64) return;
  int cu = u / 960, rem = u % 960;
  int f = rem >> 6, l = rem & 63;
  int ktm = f / 5, nt = f % 5, kt = 29 + ktm;
  int L = 1 + cu / 26, cl = cu % 26;
  int S = cl < 18 ? 20 : 19;
  int hbase = cl < 18 ? 20 * cl : 360 + 19 * (cl - 18);
  int c = 16 * nt + (l & 15);
  int row = colrow_main(c, S, hbase);
  int k = kt * 32 + (l >> 4) * 8;
  const float* src = Whh + ((size_t)L * 2048 + row) * 512 + (k - 512);
  h8 v;
#pragma unroll
  for (int j = 0; j < 8; ++j) v[j] = (_Float16)src[j];
  *(h8*)(ws + STRM_OFF + (size_t)cu * 15360 + (size_t)f * 1024 + (size_t)l * 16) = v;
}

// ---------------- main persistent kernel ----------------

__global__ __launch_bounds__(256, 1) void lstm_fused(
    const float* __restrict__ X, const float* __restrict__ Wih0,
    const float* __restrict__ Wih, const float* __restrict__ Whh,
    const float* __restrict__ bih, const float* __restrict__ bhh,
    const float* __restrict__ Wout, const float* __restrict__ bout,
    float* __restrict__ out, char* __restrict__ ws)
{
  extern __shared__ char lds[];
  const int blk = blockIdx.x;
  const int role = (blk & 7) * 32 + (blk >> 3);
  if (role >= 250) return;

  __half* hbuf = (__half*)(ws + HBUF_OFF);
  const __half* xt = (const __half*)(ws + X_OFF);
  int* rdy = (int*)(ws + RDY_OFF);
  int* dn  = (int*)(ws + DONE_OFF);

  const int tid = threadIdx.x;
  const int lane = tid & 63;
  const int wv = tid >> 6;
  const int pp = lane & 15;
  const int lg = lane >> 4;
  const int n = wv & 1, m = wv >> 1;
  const int ab0 = lg * 512 + (16 * (2 * m) + pp) * 8;
  const int ab1 = ab0 + 128;

  if (role < 16) {
    // ================= layer 0 + head =================
    const int cu = role;
    const int hbase = cu * 32;
    for (int ch = tid; ch < 9216; ch += 256) {
      int c = ch / 72, kc = (ch % 72) * 8;
      int g = (c >> 4) & 3;
      int hl = ((c >> 6) << 4) + (c & 15);
      int row = g * 512 + hbase + hl;
      const float* src = (kc < 64) ? (Wih0 + (size_t)row * 64 + kc)
                                   : (Whh + (size_t)row * 512 + (kc - 64));
      h8 v;
#pragma unroll
      for (int j = 0; j < 8; ++j) v[j] = (_Float16)src[j];
      uint32_t off = ((uint32_t)(c * 1152 + kc * 2)) ^ (uint32_t)((c & 7) << 4);
      *(h8*)(lds + off) = v;
    }
    float bias0[4];
#pragma unroll
    for (int j = 0; j < 4; ++j) {
      int row = j * 512 + hbase + n * 16 + pp;
      bias0[j] = bih[row] + bhh[row];
    }
    __syncthreads();

    float cv[2][4] = {{0.f,0.f,0.f,0.f},{0.f,0.f,0.f,0.f}};
    int* rdy0 = rdy;
    int* rdy9 = rdy + 9 * FSTR;
    int* dn0 = dn;
    int* dn9 = dn + 9 * FSTR;

    for (int t = 0; t < 266; ++t) {
      // ---- all waits, tid0 only ----
      if (tid == 0) {
        if (t >= 10) spin_ge(rdy9 + t - 10, 26);
        if (t <= 255) {
          if (t > 0) spin_ge(rdy0 + t - 1, 16);
          if (t >= 15) spin_ge(dn0 + t - 15, (t == 15) ? 16 : 42);
        }
      }
      __syncthreads();

      // ---- head for step t-10 ----
      if (t >= 10) {
        const int th = t - 10;
        const __half* h9 = hbuf + ((size_t)9 * RSLOT + ((th + 1) & 15)) * 32768;
        const int b = lane;
        const int dp = cu * 4 + wv;
        float acc = bout[dp];
        const float* wrow = Wout + (size_t)dp * 512;
#pragma unroll 8
        for (int kg = 0; kg < 64; ++kg) {
          h8 hv = ld_h8_dc(h9 + (size_t)kg * 512 + b * 8);
          f4 w0 = *(const f4*)(wrow + kg * 8);
          f4 w1 = *(const f4*)(wrow + kg * 8 + 4);
          acc += (float)hv[0]*w0[0] + (float)hv[1]*w0[1] + (float)hv[2]*w0[2] + (float)hv[3]*w0[3]
               + (float)hv[4]*w1[0] + (float)hv[5]*w1[1] + (float)hv[6]*w1[2] + (float)hv[7]*w1[3];
        }
        out[(size_t)b * 16384 + (size_t)th * 64 + dp] = acc;
      }
      // ---- layer-0 cell t ----
      if (t <= 255) {
        const __half* Ax = xt + (size_t)t * 4096;
        const __half* As = hbuf + (size_t)(t & 15) * 32768;
        f4 acc[2][4];
#pragma unroll
        for (int mi = 0; mi < 2; ++mi)
#pragma unroll
          for (int j = 0; j < 4; ++j) acc[mi][j] = (f4){0.f, 0.f, 0.f, 0.f};

#pragma unroll
        for (int kt = 0; kt < 2; ++kt) {
          h8 a0 = *(const h8*)(Ax + kt * 2048 + ab0);
          h8 a1 = *(const h8*)(Ax + kt * 2048 + ab1);
#pragma unroll
          for (int j = 0; j < 4; ++j) {
            int c = 16 * (4 * n + j) + pp;
            uint32_t off = ((uint32_t)(c * 1152 + kt * 64 + lg * 16)) ^ (uint32_t)((c & 7) << 4);
            h8 bv = *(const h8*)(lds + off);
            acc[0][j] = MFMA16(a0, bv, acc[0][j]);
            acc[1][j] = MFMA16(a1, bv, acc[1][j]);
          }
        }
#pragma unroll 4
        for (int kt = 2; kt < 18; ++kt) {
          h8 a0 = ld_h8_dc(As + (kt - 2) * 2048 + ab0);
          h8 a1 = ld_h8_dc(As + (kt - 2) * 2048 + ab1);
#pragma unroll
          for (int j = 0; j < 4; ++j) {
            int c = 16 * (4 * n + j) + pp;
            uint32_t off = ((uint32_t)(c * 1152 + kt * 64 + lg * 16)) ^ (uint32_t)((c & 7) << 4);
            h8 bv = *(const h8*)(lds + off);
            acc[0][j] = MFMA16(a0, bv, acc[0][j]);
            acc[1][j] = MFMA16(a1, bv, acc[1][j]);
          }
        }
        __half* Hd = hbuf + (size_t)((t + 1) & 15) * 32768;
        const int hg = hbase + n * 16 + pp;
#pragma unroll
        for (int mi = 0; mi < 2; ++mi) {
          int bbb = 16 * (2 * m + mi) + 4 * lg;
#pragma unroll
          for (int r = 0; r < 4; ++r) {
            float gi = sigm(acc[mi][0][r] + bias0[0]);
            float gf = sigm(acc[mi][1][r] + bias0[1]);
            float gg = tanh_f(acc[mi][2][r] + bias0[2]);
            float go = sigm(acc[mi][3][r] + bias0[3]);
            float c2 = gf * cv[mi][r] + gi * gg;
            cv[mi][r] = c2;
            st_h_dc(Hd + (size_t)(hg >> 3) * 512 + (bbb + r) * 8 + (hg & 7),
                    go * tanh_f(c2));
          }
        }
      }
      __syncthreads();   // drains vmcnt: all sc1 stores acked at L3 before flag add
      if (tid == 0) {
        if (t <= 255) {
          __hip_atomic_fetch_add(rdy0 + t, 1, __ATOMIC_RELAXED, __HIP_MEMORY_SCOPE_AGENT);
          __hip_atomic_fetch_add(dn0 + t, 1, __ATOMIC_RELAXED, __HIP_MEMORY_SCOPE_AGENT);
        }
        if (t >= 10)
          __hip_atomic_fetch_add(dn9 + (t - 9), 1, __ATOMIC_RELAXED, __HIP_MEMORY_SCOPE_AGENT);
      }
    }
    return;
  }

  // ================= layers 1..9 =================
  const int cuIdx = role - 16;
  const int L = 1 + cuIdx / 26;
  const int cl = cuIdx % 26;
  const int S = cl < 18 ? 20 : 19;
  const int hbase = cl < 18 ? 20 * cl : 360 + 19 * (cl - 18);
  const float* WihL = Wih + (size_t)(L - 1) * 1048576;
  const float* WhhL = Whh + (size_t)L * 1048576;
  const float* bihL = bih + L * 2048;
  const float* bhhL = bhh + L * 2048;

  for (int ch = tid; ch < 9280; ch += 256) {
    int c = ch / 116, kc = (ch % 116) * 8;
    int row = colrow_main(c, S, hbase);
    const float* src = (kc < 512) ? (WihL + (size_t)row * 512 + kc)
                                  : (WhhL + (size_t)row * 512 + (kc - 512));
    h8 v;
#pragma unroll
    for (int j = 0; j < 8; ++j) v[j] = (_Float16)src[j];
    uint32_t off = ((uint32_t)(c * 1856 + kc * 2)) ^ (uint32_t)((c & 7) << 4);
    *(h8*)(lds + off) = v;
  }
  float biasv[4], bsp[4];
#pragma unroll
  for (int j = 0; j < 4; ++j) {
    int row = colrow_main(16 * j + pp, S, hbase);
    biasv[j] = bihL[row] + bhhL[row];
    int rs = colrow_main(64 + 4 * (pp >> 2) + j, S, hbase);
    bsp[j] = bihL[rs] + bhhL[rs];
  }
  __syncthreads();

  int* rdyP = rdy + (L - 1) * FSTR;
  int* rdyL = rdy + L * FSTR;
  int* dnP = dn + (L - 1) * FSTR;
  int* dnL = dn + L * FSTR;
  const int ncuP = (L == 1) ? 16 : 26;
  const int dnTgt = (L == 9) ? 42 : 52;
  const int ntA = n ? 3 : 0;
  const int cA = 16 * ntA + pp, cB = cA + 16, c2c = 32 + pp;
  const char* strm = ws + STRM_OFF + (size_t)cuIdx * 15360;
  float* xch = (float*)(lds + 148480);

  float cv[2][2] = {{0.f,0.f},{0.f,0.f}};
  float csp[2][2] = {{0.f,0.f},{0.f,0.f}};

  for (int t = 0; t < 256; ++t) {
    if (tid == 0) {
      spin_ge(rdyP + t, ncuP);
      if (t > 0) spin_ge(rdyL + t - 1, 26);
      if (t >= 15) spin_ge(dnL + t - 15, (t == 15) ? 26 : dnTgt);
    }
    __syncthreads();

    const __half* Abot = hbuf + ((size_t)(L - 1) * RSLOT + ((t + 1) & 15)) * 32768;
    const __half* Asel = hbuf + ((size_t)L * RSLOT + (t & 15)) * 32768;

    f4 acc[2][3];
#pragma unroll
    for (int mi = 0; mi < 2; ++mi)
#pragma unroll
      for (int j = 0; j < 3; ++j) acc[mi][j] = (f4){0.f, 0.f, 0.f, 0.f};

#pragma unroll 4
    for (int kt = 0; kt < 16; ++kt) {
      h8 a0 = ld_h8_dc(Abot + kt * 2048 + ab0);
      h8 a1 = ld_h8_dc(Abot + kt * 2048 + ab1);
      uint32_t o0 = ((uint32_t)(cA * 1856 + kt * 64 + lg * 16)) ^ (uint32_t)((cA & 7) << 4);
      uint32_t o1 = ((uint32_t)(cB * 1856 + kt * 64 + lg * 16)) ^ (uint32_t)((cB & 7) << 4);
      h8 b0 = *(const h8*)(lds + o0);
      h8 b1 = *(const h8*)(lds + o1);
      acc[0][0] = MFMA16(a0, b0, acc[0][0]);
      acc[1][0] = MFMA16(a1, b0, acc[1][0]);
      acc[0][1] = MFMA16(a0, b1, acc[0][1]);
      acc[1][1] = MFMA16(a1, b1, acc[1][1]);
      if (n == 0) {
        uint32_t o2 = ((uint32_t)(c2c * 1856 + kt * 64 + lg * 16)) ^ (uint32_t)((c2c & 7) << 4);
        h8 b2 = *(const h8*)(lds + o2);
        acc[0][2] = MFMA16(a0, b2, acc[0][2]);
        acc[1][2] = MFMA16(a1, b2, acc[1][2]);
      }
    }
#pragma unroll 4
    for (int kt = 16; kt < 29; ++kt) {
      h8 a0 = ld_h8_dc(Asel + (kt - 16) * 2048 + ab0);
      h8 a1 = ld_h8_dc(Asel + (kt - 16) * 2048 + ab1);
      uint32_t o0 = ((uint32_t)(cA * 1856 + kt * 64 + lg * 16)) ^ (uint32_t)((cA & 7) << 4);
      uint32_t o1 = ((uint32_t)(cB * 1856 + kt * 64 + lg * 16)) ^ (uint32_t)((cB & 7) << 4);
      h8 b0 = *(const h8*)(lds + o0);
      h8 b1 = *(const h8*)(lds + o1);
      acc[0][0] = MFMA16(a0, b0, acc[0][0]);
      acc[1][0] = MFMA16(a1, b0, acc[1][0]);
      acc[0][1] = MFMA16(a0, b1, acc[0][1]);
      acc[1][1] = MFMA16(a1, b1, acc[1][1]);
      if (n == 1) {
        uint32_t o2 = ((uint32_t)(c2c * 1856 + kt * 64 + lg * 16)) ^ (uint32_t)((c2c & 7) << 4);
        h8 b2 = *(const h8*)(lds + o2);
        acc[0][2] = MFMA16(a0, b2, acc[0][2]);
        acc[1][2] = MFMA16(a1, b2, acc[1][2]);
      }
    }
#pragma unroll
    for (int kt = 29; kt < 32; ++kt) {
      h8 a0 = ld_h8_dc(Asel + (kt - 16) * 2048 + ab0);
      h8 a1 = ld_h8_dc(Asel + (kt - 16) * 2048 + ab1);
      h8 b0 = *(const h8*)(strm + ((kt - 29) * 5 + ntA) * 1024 + lane * 16);
      h8 b1 = *(const h8*)(strm + ((kt - 29) * 5 + ntA + 1) * 1024 + lane * 16);
      acc[0][0] = MFMA16(a0, b0, acc[0][0]);
      acc[1][0] = MFMA16(a1, b0, acc[1][0]);
      acc[0][1] = MFMA16(a0, b1, acc[0][1]);
      acc[1][1] = MFMA16(a1, b1, acc[1][1]);
      if (n == 1) {
        h8 b2 = *(const h8*)(strm + ((kt - 29) * 5 + 2) * 1024 + lane * 16);
        acc[0][2] = MFMA16(a0, b2, acc[0][2]);
        acc[1][2] = MFMA16(a1, b2, acc[1][2]);
      }
    }

    {
      int idx = 0;
#pragma unroll
      for (int mi = 0; mi < 2; ++mi)
#pragma unroll
        for (int ntl = 0; ntl < 3; ++ntl)
#pragma unroll
          for (int rj = 0; rj < 2; ++rj) {
            float sv = (n == 0) ? acc[mi][ntl][2 + rj] : acc[mi][ntl][rj];
            xch[(wv * 12 + idx) * 64 + lane] = sv;
            ++idx;
          }
    }
    __syncthreads();
    float F[2][5][2];
    {
      const int pw = wv ^ 1;
#pragma unroll
      for (int mi = 0; mi < 2; ++mi)
#pragma unroll
        for (int rj = 0; rj < 2; ++rj) {
          float r0 = xch[(pw * 12 + (mi * 3 + 0) * 2 + rj) * 64 + lane];
          float r1 = xch[(pw * 12 + (mi * 3 + 1) * 2 + rj) * 64 + lane];
          float r2 = xch[(pw * 12 + (mi * 3 + 2) * 2 + rj) * 64 + lane];
          float o0, o1, o2;
          if (n == 0) { o0 = acc[mi][0][rj]; o1 = acc[mi][1][rj]; o2 = acc[mi][2][rj]; }
          else        { o0 = acc[mi][0][2 + rj]; o1 = acc[mi][1][2 + rj]; o2 = acc[mi][2][2 + rj]; }
          if (n == 0) {
            F[mi][0][rj] = o0; F[mi][1][rj] = o1; F[mi][2][rj] = o2 + r2;
            F[mi][3][rj] = r0; F[mi][4][rj] = r1;
          } else {
            F[mi][0][rj] = r0; F[mi][1][rj] = r1; F[mi][2][rj] = o2 + r2;
            F[mi][3][rj] = o0; F[mi][4][rj] = o1;
          }
        }
    }

    __half* Hd = hbuf + ((size_t)L * RSLOT + ((t + 1) & 15)) * 32768;
    const int rrb = n ? 2 : 0;
    const int pm = lane & 3;
#pragma unroll
    for (int mi = 0; mi < 2; ++mi) {
#pragma unroll
      for (int rj = 0; rj < 2; ++rj) {
        int bbb = 16 * (2 * m + mi) + 4 * lg + rrb + rj;
        float gi = sigm(F[mi][0][rj] + biasv[0]);
        float gf = sigm(F[mi][1][rj] + biasv[1]);
        float gg = tanh_f(F[mi][2][rj] + biasv[2]);
        float go = sigm(F[mi][3][rj] + biasv[3]);
        float cc = gf * cv[mi][rj] + gi * gg;
        cv[mi][rj] = cc;
        {
          int hg = hbase + pp;
          st_h_dc(Hd + (size_t)(hg >> 3) * 512 + bbb * 8 + (hg & 7),
                  go * tanh_f(cc));
        }
        float va = F[mi][4][rj];
        float vb = __shfl_xor(va, 1);
        float vc = __shfl_xor(va, 2);
        float vd = __shfl_xor(vb, 2);
        float q0 = (pm & 2) ? ((pm & 1) ? vd : vc) : ((pm & 1) ? vb : va);
        float q1 = (pm & 2) ? ((pm & 1) ? vc : vd) : ((pm & 1) ? va : vb);
        float q2 = (pm & 2) ? ((pm & 1) ? vb : va) : ((pm & 1) ? vd : vc);
        float q3 = (pm & 2) ? ((pm & 1) ? va : vb) : ((pm & 1) ? vc : vd);
        float si = sigm(q0 + bsp[0]);
        float sf = sigm(q1 + bsp[1]);
        float sg = tanh_f(q2 + bsp[2]);
        float so = sigm(q3 + bsp[3]);
        float c3 = sf * csp[mi][rj] + si * sg;
        csp[mi][rj] = c3;
        float hs = so * tanh_f(c3);
        int hj = 16 + (pp >> 2);
        if (pm == 0 && hj < S) {
          int hg = hbase + hj;
          st_h_dc(Hd + (size_t)(hg >> 3) * 512 + bbb * 8 + (hg & 7), hs);
        }
      }
    }

    __syncthreads();   // drains vmcnt: sc1 stores at L3 before flag adds
    if (tid == 0) {
      __hip_atomic_fetch_add(rdyL + t, 1, __ATOMIC_RELAXED, __HIP_MEMORY_SCOPE_AGENT);
      __hip_atomic_fetch_add(dnP + t + 1, 1, __ATOMIC_RELAXED, __HIP_MEMORY_SCOPE_AGENT);
      __hip_atomic_fetch_add(dnL + t, 1, __ATOMIC_RELAXED, __HIP_MEMORY_SCOPE_AGENT);
    }
  }
}

// ---------------- host ----------------

extern "C" void kernel_launch(void* const* d_in, const int* in_sizes, int n_in,
                              void* d_out, int out_size, void* d_ws, size_t ws_size,
                              hipStream_t stream) {
  const float* X    = (const float*)d_in[0];
  const float* Wih0 = (const float*)d_in[1];
  const float* Wih  = (const float*)d_in[2];
  const float* Whh  = (const float*)d_in[3];
  const float* bihp = (const float*)d_in[4];
  const float* bhhp = (const float*)d_in[5];
  const float* Wout = (const float*)d_in[6];
  const float* bout = (const float*)d_in[7];
  float* out = (float*)d_out;
  char* ws = (char*)d_ws;
  (void)in_sizes; (void)n_in; (void)out_size;
  if (ws_size < WS_NEED) return;

  hipFuncSetAttribute((const void*)lstm_fused,
                      hipFuncAttributeMaxDynamicSharedMemorySize, 163840);

  zero_kernel<<<661, 256, 0, stream>>>(ws);
  xprep_kernel<<<512, 256, 0, stream>>>(X, ws);
  wsprep_kernel<<<878, 256, 0, stream>>>(Whh, ws);
  lstm_fused<<<256, 256, 163840, stream>>>(X, Wih0, Wih, Whh, bihp, bhhp,
                                           Wout, bout, out, ws);
}